// Round 6
// baseline (147.658 us; speedup 1.0000x reference)
//
#include <hip/hip_runtime.h>
#include <hip/hip_bf16.h>
#include <math.h>

#define D_MODEL 768
#define HEADS 12
#define DK 64
#define SEQ 2048
#define BATCH 2
#define MTOT (BATCH * SEQ)   // 4096
#define QSCALE 0.18033688011112042f   // 0.125 * log2(e): softmax in exp2 domain

using short8 = __attribute__((ext_vector_type(8))) short;
using us4    = __attribute__((ext_vector_type(4))) unsigned short;
using f32x4  = __attribute__((ext_vector_type(4))) float;

// ---------------- helpers ---------------------------------------------------
static __device__ __forceinline__ unsigned f2bf2(float x, float y) {
    __hip_bfloat162 t = __float22bfloat162_rn(float2{x, y});
    return *reinterpret_cast<unsigned*>(&t);
}
static __device__ __forceinline__ unsigned short f2bf1(float x) {
    __hip_bfloat16 t = __float2bfloat16(x);
    return *reinterpret_cast<unsigned short*>(&t);
}
static __device__ __forceinline__ short8 cvt8(float4 a, float4 b) {
    union { unsigned u[4]; short8 s; } r;
    r.u[0] = f2bf2(a.x, a.y);
    r.u[1] = f2bf2(a.z, a.w);
    r.u[2] = f2bf2(b.x, b.y);
    r.u[3] = f2bf2(b.z, b.w);
    return r.s;
}
static __device__ __forceinline__ float fast_exp2(float x) {
#if __has_builtin(__builtin_amdgcn_exp2f)
    return __builtin_amdgcn_exp2f(x);
#else
    return __expf(x * 0.6931471805599453f);
#endif
}

static __device__ __forceinline__ void gload_lds16(const void* g, void* l) {
    __builtin_amdgcn_global_load_lds(
        (const __attribute__((address_space(1))) void*)g,
        (__attribute__((address_space(3))) void*)l, 16, 0, 0);
}

// barrier draining LDS ops only (VMEM prefetch stays in flight unless a
// register dependency already retired it)
static __device__ __forceinline__ void barrier_lgkm() {
    asm volatile("s_waitcnt lgkmcnt(0)" ::: "memory");
    __builtin_amdgcn_s_barrier();
    __builtin_amdgcn_sched_barrier(0);
}
static __device__ __forceinline__ void barrier_vm0() {
    asm volatile("s_waitcnt vmcnt(0)" ::: "memory");
    __builtin_amdgcn_s_barrier();
    __builtin_amdgcn_sched_barrier(0);
}

// ---------------- pre-pass: W[k][n] fp32 -> Wt[n][k] bf16 (4 W's fused) -----
__global__ __launch_bounds__(256) void cvt_wt_k(
    const float* __restrict__ Wq, const float* __restrict__ Wk,
    const float* __restrict__ Wv, const float* __restrict__ Wo,
    unsigned short* __restrict__ Wqt, unsigned short* __restrict__ Wkt,
    unsigned short* __restrict__ Wvt, unsigned short* __restrict__ Wot)
{
    const int z = blockIdx.z;
    const float* W = z == 0 ? Wq : z == 1 ? Wk : z == 2 ? Wv : Wo;
    unsigned short* Wt = z == 0 ? Wqt : z == 1 ? Wkt : z == 2 ? Wvt : Wot;
    __shared__ float t[32][33];
    const int n0 = blockIdx.x * 32, k0 = blockIdx.y * 32;
    const int tx = threadIdx.x & 31;
    const int ty0 = (threadIdx.x >> 5) * 4;
    #pragma unroll
    for (int j = 0; j < 4; ++j)
        t[ty0 + j][tx] = W[(size_t)(k0 + ty0 + j) * D_MODEL + n0 + tx];
    __syncthreads();
    #pragma unroll
    for (int j = 0; j < 4; ++j)
        Wt[(size_t)(n0 + ty0 + j) * D_MODEL + k0 + tx] = f2bf1(t[tx][ty0 + j]);
}

// ---------------- bf16 MFMA GEMM: 64x64 tile, BK=64, 2 bufs, unroll-2 -------
// A_FP32: A is fp32, reg-staged + converted to bf16 LDS (write-late).
// else:   A is bf16, staged via global_load_lds (pre-swizzled source).
template <int A_FP32, int OUT_BF16>
static __device__ __forceinline__ void gemm_body(
    const void* __restrict__ Av, const unsigned short* __restrict__ Wt,
    const float* __restrict__ bias, void* __restrict__ C, float scale)
{
    __shared__ __align__(16) char gsm[32768];   // A: 0 + buf*8192 ; B: 16384 + buf*8192

    const int tid  = threadIdx.x;
    const int w    = tid >> 6;
    const int lane = tid & 63;
    const int g    = lane >> 4, c = lane & 15;
    const int wr   = w >> 1, wc = w & 1;
    const int brow = blockIdx.y * 64;
    const int bcol = blockIdx.x * 64;

    f32x4 acc[2][2] = {{f32x4{0,0,0,0}, f32x4{0,0,0,0}},
                       {f32x4{0,0,0,0}, f32x4{0,0,0,0}}};

    // hoisted read bases: row&7 == c&7 for every fragment row
    const int xc  = (c & 7) << 4;
    const int rb0 = c * 128 + ((g * 16) ^ xc);            // kstep 0
    const int rb1 = c * 128 + ((64 + g * 16) ^ xc);       // kstep 1
    const int a0 = rb0 + wr * 4096, a1 = rb1 + wr * 4096;
    const int b0r = rb0 + 16384 + wc * 4096, b1r = rb1 + 16384 + wc * 4096;

    // B staging (gload_lds, linear dest + pre-swizzled source)
    int bsrow[2], bsoff[2], bsdst[2];
    #pragma unroll
    for (int r = 0; r < 2; ++r) {
        int phys = (w + 4 * r) * 1024 + lane * 16;
        int row  = phys >> 7;
        int slot = (phys >> 4) & 7;
        bsrow[r] = row;
        bsoff[r] = (slot ^ (row & 7)) * 8;
        bsdst[r] = (w + 4 * r) * 1024;
    }
    // A staging
    // fp32 path: thread owns row ar, 16 k-elems at ac
    const int ar = tid >> 2;
    const int ac = (tid & 3) << 4;
    int awa[2];
    #pragma unroll
    for (int i = 0; i < 2; ++i)
        awa[i] = ar * 128 + (((ac << 1) + 16 * i) ^ ((ar & 7) << 4));
    const float* Ap32 = (const float*)Av + (size_t)(brow + ar) * D_MODEL + ac;
    const unsigned short* Ap16base = (const unsigned short*)Av;

    float4 ra0, ra1, ra2, ra3;   // fp32 A in-flight regs

    auto stageB = [&](int k0, int buf) {
        #pragma unroll
        for (int r = 0; r < 2; ++r)
            gload_lds16(Wt + (size_t)(bcol + bsrow[r]) * D_MODEL + k0 + bsoff[r],
                        gsm + 16384 + buf * 8192 + bsdst[r]);
    };
    auto stageA16 = [&](int k0, int buf) {
        #pragma unroll
        for (int r = 0; r < 2; ++r)
            gload_lds16(Ap16base + (size_t)(brow + bsrow[r]) * D_MODEL + k0 + bsoff[r],
                        gsm + buf * 8192 + bsdst[r]);
    };
    auto loadA32 = [&](int k0) {
        ra0 = *(const float4*)(Ap32 + k0);
        ra1 = *(const float4*)(Ap32 + k0 + 4);
        ra2 = *(const float4*)(Ap32 + k0 + 8);
        ra3 = *(const float4*)(Ap32 + k0 + 12);
    };
    auto writeA32 = [&](int buf) {   // reg-dep wait retires B gloads issued earlier
        *(short8*)(gsm + buf * 8192 + awa[0]) = cvt8(ra0, ra1);
        *(short8*)(gsm + buf * 8192 + awa[1]) = cvt8(ra2, ra3);
    };

    // prologue: fill buf0
    if (A_FP32) {
        stageB(0, 0);
        loadA32(0);
        writeA32(0);
        barrier_lgkm();
    } else {
        stageA16(0, 0);
        stageB(0, 0);
        barrier_vm0();
    }

    for (int k0 = 0; k0 < D_MODEL; k0 += 128) {
        #pragma unroll
        for (int u = 0; u < 2; ++u) {
            const int kc = k0 + u * 64;
            const int kn = min(kc + 64, D_MODEL - 64);   // tail dup: harmless
            if (A_FP32) {
                stageB(kn, u ^ 1);
                loadA32(kn);
            } else {
                stageA16(kn, u ^ 1);
                stageB(kn, u ^ 1);
            }
            __builtin_amdgcn_sched_barrier(0);

            #pragma unroll
            for (int kstep = 0; kstep < 2; ++kstep) {
                short8 af[2], bf[2];
                #pragma unroll
                for (int m = 0; m < 2; ++m)
                    af[m] = *(const short8*)(gsm + u * 8192 + m * 2048 +
                                             (kstep ? a1 : a0));
                #pragma unroll
                for (int n = 0; n < 2; ++n)
                    bf[n] = *(const short8*)(gsm + u * 8192 + n * 2048 +
                                             (kstep ? b1r : b0r));
                #pragma unroll
                for (int m = 0; m < 2; ++m)
                    #pragma unroll
                    for (int n = 0; n < 2; ++n)
                        acc[m][n] = __builtin_amdgcn_mfma_f32_16x16x32_bf16(
                                        af[m], bf[n], acc[m][n], 0, 0, 0);
            }
            if (A_FP32) {
                writeA32(u ^ 1);
                barrier_lgkm();
            } else {
                barrier_vm0();
            }
        }
    }

    #pragma unroll
    for (int m = 0; m < 2; ++m)
        #pragma unroll
        for (int n = 0; n < 2; ++n) {
            const int col = bcol + wc * 32 + n * 16 + c;
            const float bval = bias[col];
            #pragma unroll
            for (int j = 0; j < 4; ++j) {
                const int row = brow + wr * 32 + m * 16 + g * 4 + j;
                const float val = (acc[m][n][j] + bval) * scale;
                if (OUT_BF16)
                    ((unsigned short*)C)[(size_t)row * D_MODEL + col] = f2bf1(val);
                else
                    ((float*)C)[(size_t)row * D_MODEL + col] = val;
            }
        }
}

__global__ __launch_bounds__(256) void gemm_qkv_k(
    const float* __restrict__ query, const float* __restrict__ key,
    const float* __restrict__ value,
    const unsigned short* __restrict__ Wqt, const unsigned short* __restrict__ Wkt,
    const unsigned short* __restrict__ Wvt,
    const float* __restrict__ bq, const float* __restrict__ bk,
    const float* __restrict__ bv,
    unsigned short* __restrict__ qb, unsigned short* __restrict__ kb,
    unsigned short* __restrict__ vb)
{
    const int z = blockIdx.z;
    const void* A            = z == 0 ? (const void*)query : z == 1 ? (const void*)key : (const void*)value;
    const unsigned short* Wt = z == 0 ? Wqt : z == 1 ? Wkt : Wvt;
    const float* bias        = z == 0 ? bq  : z == 1 ? bk  : bv;
    unsigned short* C        = z == 0 ? qb  : z == 1 ? kb  : vb;
    gemm_body<1, 1>(A, Wt, bias, C, z == 0 ? QSCALE : 1.0f);
}

__global__ __launch_bounds__(256) void gemm_o_k(
    const unsigned short* __restrict__ A, const unsigned short* __restrict__ Wt,
    const float* __restrict__ bias, float* __restrict__ C)
{
    gemm_body<0, 0>(A, Wt, bias, C, 1.0f);
}

// ---------------- Flash attention: 2 bufs, unroll-2, lane-local defer -------
// grid 768 (flat, XCD-chunk swizzled), 256 thr = 4 waves; wave w: q-rows [16w,16w+16)
// LDS map (40 KB): K: 0 + buf*8192 ; V^T: 16384 + buf*8192 ; P: 32768 + w*2048
__global__ __launch_bounds__(256) void attn_mfma_k(
    const unsigned short* __restrict__ q, const unsigned short* __restrict__ k,
    const unsigned short* __restrict__ v, unsigned short* __restrict__ ctx)
{
    __shared__ __align__(16) char sm[40960];

    const int tid  = threadIdx.x;
    const int w    = tid >> 6;
    const int lane = tid & 63;
    const int g    = lane >> 4;
    const int c    = lane & 15;

    const int bid = blockIdx.x;
    const int swz = (bid & 7) * 96 + (bid >> 3);
    const int qt  = swz & 31;
    const int hb  = swz >> 5;
    const int h   = hb % HEADS;
    const int b   = hb / HEADS;
    const int q0  = qt * 64;
    const int NT  = SEQ / 64;   // 32

    // Q strip A-frags (pre-scaled by QSCALE in the projection GEMM)
    short8 qf0, qf1;
    {
        const int qrow = q0 + (w << 4) + c;
        const unsigned short* qp = q + (size_t)(b * SEQ + qrow) * D_MODEL + h * DK;
        qf0 = *(const short8*)(qp + g * 8);
        qf1 = *(const short8*)(qp + 32 + g * 8);
    }

    float m_run[4] = {-INFINITY, -INFINITY, -INFINITY, -INFINITY};
    f32x4 lacc = f32x4{0, 0, 0, 0};
    f32x4 o[4] = {f32x4{0,0,0,0}, f32x4{0,0,0,0}, f32x4{0,0,0,0}, f32x4{0,0,0,0}};
    const short8 ONES = {0x3F80, 0x3F80, 0x3F80, 0x3F80,
                         0x3F80, 0x3F80, 0x3F80, 0x3F80};

    // hoisted LDS read bases (row&7 == c&7 for K/V/P fragment rows)
    const int xc = (c & 7) << 4;
    const int rb0 = c * 128 + ((g * 16) ^ xc);        // kstep 0
    const int rb1 = c * 128 + ((64 + g * 16) ^ xc);   // kstep 1
    const int bp0 = 32768 + w * 2048 + rb0;           // P read bases
    const int bp1 = 32768 + w * 2048 + rb1;

    // P write addresses (per reg)
    int pwa[4];
    #pragma unroll
    for (int r = 0; r < 4; ++r) {
        const int row = (g << 2) + r;
        pwa[r] = 32768 + w * 2048 + row * 128 + ((c << 3) ^ ((row & 7) << 4));
    }
    // V write addresses (per j)
    const int cv = tid & 15, vd0 = (tid >> 4) << 2;
    int vwa[4];
    #pragma unroll
    for (int j = 0; j < 4; ++j) {
        const int row = vd0 + j;
        vwa[j] = 16384 + row * 128 + ((cv << 3) ^ ((row & 7) << 4));
    }
    // K staging geometry (linear dest + pre-swizzled source)
    int kdst[2];
    const unsigned short* kg[2];
    {
        const unsigned short* kbase = k + (size_t)(b * SEQ) * D_MODEL + h * DK;
        #pragma unroll
        for (int r = 0; r < 2; ++r) {
            int phys = (w + 4 * r) * 1024 + lane * 16;
            int row  = phys >> 7;
            int slot = (phys >> 4) & 7;
            kdst[r]  = (w + 4 * r) * 1024;
            kg[r]    = kbase + (size_t)row * D_MODEL + (slot ^ (row & 7)) * 8;
        }
    }
    const unsigned short* vg = v + (size_t)(b * SEQ + cv) * D_MODEL + h * DK + vd0;
    const int TS = 64 * D_MODEL;   // tile stride (elements)

    us4 va, vb_, vc, vd;   // V in-flight regs (single set, write-late)

    // ---- prologue: tile 0 ----
    gload_lds16(kg[0], sm + kdst[0]);
    gload_lds16(kg[1], sm + kdst[1]);
    va  = *(const us4*)(vg);
    vb_ = *(const us4*)(vg + 16 * D_MODEL);
    vc  = *(const us4*)(vg + 32 * D_MODEL);
    vd  = *(const us4*)(vg + 48 * D_MODEL);
    kg[0] += TS; kg[1] += TS; vg += TS;
    #pragma unroll
    for (int j = 0; j < 4; ++j) {
        uint2 pk;
        pk.x = (unsigned)va[j] | ((unsigned)vb_[j] << 16);
        pk.y = (unsigned)vc[j] | ((unsigned)vd[j] << 16);
        *(uint2*)(sm + vwa[j]) = pk;
    }
    barrier_lgkm();

    for (int kt = 0; kt < NT; kt += 2) {
        #pragma unroll
        for (int u = 0; u < 2; ++u) {
            // ---- prefetch tile kt+u+1 (tail overruns stay inside d_ws, unused) ----
            gload_lds16(kg[0], sm + (u ^ 1) * 8192 + kdst[0]);
            gload_lds16(kg[1], sm + (u ^ 1) * 8192 + kdst[1]);
            va  = *(const us4*)(vg);
            vb_ = *(const us4*)(vg + 16 * D_MODEL);
            vc  = *(const us4*)(vg + 32 * D_MODEL);
            vd  = *(const us4*)(vg + 48 * D_MODEL);
            kg[0] += TS; kg[1] += TS; vg += TS;
            __builtin_amdgcn_sched_barrier(0);

            // ---- S = Q @ K^T ----
            f32x4 sacc[4] = {f32x4{0,0,0,0}, f32x4{0,0,0,0},
                             f32x4{0,0,0,0}, f32x4{0,0,0,0}};
            #pragma unroll
            for (int kstep = 0; kstep < 2; ++kstep) {
                short8 af = kstep ? qf1 : qf0;
                #pragma unroll
                for (int ks = 0; ks < 4; ++ks) {
                    short8 bf = *(const short8*)(sm + u * 8192 + ks * 2048 +
                                                 (kstep ? rb1 : rb0));
                    sacc[ks] = __builtin_amdgcn_mfma_f32_16x16x32_bf16(
                                   af, bf, sacc[ks], 0, 0, 0);
                }
            }

            // ---- defer-max check: lane-local, ZERO cross-lane ops ----
            float rm[4], dm;
            #pragma unroll
            for (int reg = 0; reg < 4; ++reg)
                rm[reg] = fmaxf(fmaxf(sacc[0][reg], sacc[1][reg]),
                                fmaxf(sacc[2][reg], sacc[3][reg]));
            dm = fmaxf(fmaxf(rm[0] - m_run[0], rm[1] - m_run[1]),
                       fmaxf(rm[2] - m_run[2], rm[3] - m_run[3]));
            if (__any(dm > 11.0f)) {   // rare slow path: full row-max + rescale
                #pragma unroll
                for (int reg = 0; reg < 4; ++reg) {
                    float mx = rm[reg];
                    mx = fmaxf(mx, __shfl_xor(mx, 1));
                    mx = fmaxf(mx, __shfl_xor(mx, 2));
                    mx = fmaxf(mx, __shfl_xor(mx, 4));
                    mx = fmaxf(mx, __shfl_xor(mx, 8));
                    const float mnew = fmaxf(m_run[reg], mx);
                    const float sc = fast_exp2(m_run[reg] - mnew);
                    m_run[reg] = mnew;
                    lacc[reg] *= sc;
                    o[0][reg] *= sc;
                    o[1][reg] *= sc;
                    o[2][reg] *= sc;
                    o[3][reg] *= sc;
                }
            }
            #pragma unroll
            for (int reg = 0; reg < 4; ++reg) {
                const float m = m_run[reg];
                float p0 = fast_exp2(sacc[0][reg] - m);
                float p1 = fast_exp2(sacc[1][reg] - m);
                float p2 = fast_exp2(sacc[2][reg] - m);
                float p3 = fast_exp2(sacc[3][reg] - m);
                uint2 pw;
                pw.x = f2bf2(p0, p1);
                pw.y = f2bf2(p2, p3);
                *(uint2*)(sm + pwa[reg]) = pw;
            }

            // ---- O += P @ V ; l += P @ ones ----
            #pragma unroll
            for (int kstep = 0; kstep < 2; ++kstep) {
                short8 paf = *(const short8*)(sm + (kstep ? bp1 : bp0));
                lacc = __builtin_amdgcn_mfma_f32_16x16x32_bf16(paf, ONES, lacc, 0, 0, 0);
                #pragma unroll
                for (int dsub = 0; dsub < 4; ++dsub) {
                    short8 vbf = *(const short8*)(sm + 16384 + u * 8192 +
                                                  dsub * 2048 + (kstep ? rb1 : rb0));
                    o[dsub] = __builtin_amdgcn_mfma_f32_16x16x32_bf16(
                                  paf, vbf, o[dsub], 0, 0, 0);
                }
            }

            // ---- V(kt+u+1) regs -> LDS (reg-dep retires this tile's prefetch) ----
            #pragma unroll
            for (int j = 0; j < 4; ++j) {
                uint2 pk;
                pk.x = (unsigned)va[j] | ((unsigned)vb_[j] << 16);
                pk.y = (unsigned)vc[j] | ((unsigned)vd[j] << 16);
                *(uint2*)(sm + (u ^ 1) * 8192 + vwa[j]) = pk;
            }
            barrier_lgkm();
        }
    }

    // ---- normalize, store ctx as bf16 ----
    #pragma unroll
    for (int reg = 0; reg < 4; ++reg) {
        const int qrow = q0 + (w << 4) + (g << 2) + reg;
        unsigned short* cb = ctx + (size_t)(b * SEQ + qrow) * D_MODEL + h * DK;
        const float invl = 1.f / lacc[reg];
        #pragma unroll
        for (int dsub = 0; dsub < 4; ++dsub)
            cb[dsub * 16 + c] = f2bf1(o[dsub][reg] * invl);
    }
}

// ---------------------------------------------------------------------------
extern "C" void kernel_launch(void* const* d_in, const int* in_sizes, int n_in,
                              void* d_out, int out_size, void* d_ws, size_t ws_size,
                              hipStream_t stream) {
    const float* query = (const float*)d_in[0];
    const float* key   = (const float*)d_in[1];
    const float* value = (const float*)d_in[2];
    const float* Wq = (const float*)d_in[3];
    const float* bq = (const float*)d_in[4];
    const float* Wk = (const float*)d_in[5];
    const float* bk = (const float*)d_in[6];
    const float* Wv = (const float*)d_in[7];
    const float* bv = (const float*)d_in[8];
    const float* Wo = (const float*)d_in[9];
    const float* bo = (const float*)d_in[10];
    float* out = (float*)d_out;

    const size_t mat = (size_t)MTOT * D_MODEL;      // 3.145M elems
    unsigned short* qb  = (unsigned short*)d_ws;    // projected Q/K/V (bf16)
    unsigned short* kb  = qb + mat;
    unsigned short* vb  = kb + mat;
    unsigned short* cb  = vb + mat;                 // context (bf16)
    unsigned short* Wqt = cb + mat;                 // transposed bf16 weights
    unsigned short* Wkt = Wqt + D_MODEL * D_MODEL;
    unsigned short* Wvt = Wkt + D_MODEL * D_MODEL;
    unsigned short* Wot = Wvt + D_MODEL * D_MODEL;

    cvt_wt_k<<<dim3(D_MODEL / 32, D_MODEL / 32, 4), 256, 0, stream>>>(
        Wq, Wk, Wv, Wo, Wqt, Wkt, Wvt, Wot);

    gemm_qkv_k<<<dim3(D_MODEL / 64, MTOT / 64, 3), 256, 0, stream>>>(
        query, key, value, Wqt, Wkt, Wvt, bq, bk, bv, qb, kb, vb);

    attn_mfma_k<<<dim3(SEQ / 64 * HEADS * BATCH), 256, 0, stream>>>(qb, kb, vb, cb);

    gemm_o_k<<<dim3(D_MODEL / 64, MTOT / 64), 256, 0, stream>>>(cb, Wot, bo, out);
}

// Round 7
// 135.182 us; speedup vs baseline: 1.0923x; 1.0923x over previous
//
#include <hip/hip_runtime.h>
#include <hip/hip_bf16.h>
#include <math.h>

#define D_MODEL 768
#define HEADS 12
#define DK 64
#define SEQ 2048
#define BATCH 2
#define MTOT (BATCH * SEQ)   // 4096
#define QSCALE 0.18033688011112042f   // 0.125 * log2(e): softmax in exp2 domain

using short8 = __attribute__((ext_vector_type(8))) short;
using us4    = __attribute__((ext_vector_type(4))) unsigned short;
using f32x4  = __attribute__((ext_vector_type(4))) float;

// ---------------- helpers ---------------------------------------------------
static __device__ __forceinline__ unsigned f2bf2(float x, float y) {
    __hip_bfloat162 t = __float22bfloat162_rn(float2{x, y});
    return *reinterpret_cast<unsigned*>(&t);
}
static __device__ __forceinline__ unsigned short f2bf1(float x) {
    __hip_bfloat16 t = __float2bfloat16(x);
    return *reinterpret_cast<unsigned short*>(&t);
}
static __device__ __forceinline__ short8 cvt8(float4 a, float4 b) {
    union { unsigned u[4]; short8 s; } r;
    r.u[0] = f2bf2(a.x, a.y);
    r.u[1] = f2bf2(a.z, a.w);
    r.u[2] = f2bf2(b.x, b.y);
    r.u[3] = f2bf2(b.z, b.w);
    return r.s;
}
static __device__ __forceinline__ float fast_exp2(float x) {
#if __has_builtin(__builtin_amdgcn_exp2f)
    return __builtin_amdgcn_exp2f(x);
#else
    return __expf(x * 0.6931471805599453f);
#endif
}

static __device__ __forceinline__ void gload_lds16(const void* g, void* l) {
    __builtin_amdgcn_global_load_lds(
        (const __attribute__((address_space(1))) void*)g,
        (__attribute__((address_space(3))) void*)l, 16, 0, 0);
}

// barrier draining LDS ops only (VMEM prefetch stays in flight unless a
// register dependency already retired it)
static __device__ __forceinline__ void barrier_lgkm() {
    asm volatile("s_waitcnt lgkmcnt(0)" ::: "memory");
    __builtin_amdgcn_s_barrier();
    __builtin_amdgcn_sched_barrier(0);
}
static __device__ __forceinline__ void barrier_vm0() {
    asm volatile("s_waitcnt vmcnt(0)" ::: "memory");
    __builtin_amdgcn_s_barrier();
    __builtin_amdgcn_sched_barrier(0);
}

// ---------------- pre-pass: W[k][n] fp32 -> Wt[n][k] bf16 (4 W's fused) -----
__global__ __launch_bounds__(256) void cvt_wt_k(
    const float* __restrict__ Wq, const float* __restrict__ Wk,
    const float* __restrict__ Wv, const float* __restrict__ Wo,
    unsigned short* __restrict__ Wqt, unsigned short* __restrict__ Wkt,
    unsigned short* __restrict__ Wvt, unsigned short* __restrict__ Wot)
{
    const int z = blockIdx.z;
    const float* W = z == 0 ? Wq : z == 1 ? Wk : z == 2 ? Wv : Wo;
    unsigned short* Wt = z == 0 ? Wqt : z == 1 ? Wkt : z == 2 ? Wvt : Wot;
    __shared__ float t[32][33];
    const int n0 = blockIdx.x * 32, k0 = blockIdx.y * 32;
    const int tx = threadIdx.x & 31;
    const int ty0 = (threadIdx.x >> 5) * 4;
    #pragma unroll
    for (int j = 0; j < 4; ++j)
        t[ty0 + j][tx] = W[(size_t)(k0 + ty0 + j) * D_MODEL + n0 + tx];
    __syncthreads();
    #pragma unroll
    for (int j = 0; j < 4; ++j)
        Wt[(size_t)(n0 + ty0 + j) * D_MODEL + k0 + tx] = f2bf1(t[tx][ty0 + j]);
}

// ---------------- bf16 MFMA GEMM: 64x64 tile, BK=64, 2 bufs, unroll-2 -------
// A_FP32: A is fp32, reg-staged + converted to bf16 LDS (write-late).
// else:   A is bf16, staged via global_load_lds (pre-swizzled source).
template <int A_FP32, int OUT_BF16>
static __device__ __forceinline__ void gemm_body(
    const void* __restrict__ Av, const unsigned short* __restrict__ Wt,
    const float* __restrict__ bias, void* __restrict__ C, float scale,
    int brow, int bcol)
{
    __shared__ __align__(16) char gsm[32768];   // A: 0 + buf*8192 ; B: 16384 + buf*8192

    const int tid  = threadIdx.x;
    const int w    = tid >> 6;
    const int lane = tid & 63;
    const int g    = lane >> 4, c = lane & 15;
    const int wr   = w >> 1, wc = w & 1;

    f32x4 acc[2][2] = {{f32x4{0,0,0,0}, f32x4{0,0,0,0}},
                       {f32x4{0,0,0,0}, f32x4{0,0,0,0}}};

    // hoisted read bases: row&7 == c&7 for every fragment row
    const int xc  = (c & 7) << 4;
    const int rb0 = c * 128 + ((g * 16) ^ xc);            // kstep 0
    const int rb1 = c * 128 + ((64 + g * 16) ^ xc);       // kstep 1
    const int a0 = rb0 + wr * 4096, a1 = rb1 + wr * 4096;
    const int b0r = rb0 + 16384 + wc * 4096, b1r = rb1 + 16384 + wc * 4096;

    // B staging (gload_lds, linear dest + pre-swizzled source)
    int bsrow[2], bsoff[2], bsdst[2];
    #pragma unroll
    for (int r = 0; r < 2; ++r) {
        int phys = (w + 4 * r) * 1024 + lane * 16;
        int row  = phys >> 7;
        int slot = (phys >> 4) & 7;
        bsrow[r] = row;
        bsoff[r] = (slot ^ (row & 7)) * 8;
        bsdst[r] = (w + 4 * r) * 1024;
    }
    // A staging (fp32 path): thread owns row ar, 16 k-elems at ac
    const int ar = tid >> 2;
    const int ac = (tid & 3) << 4;
    int awa[2];
    #pragma unroll
    for (int i = 0; i < 2; ++i)
        awa[i] = ar * 128 + (((ac << 1) + 16 * i) ^ ((ar & 7) << 4));
    const float* Ap32 = (const float*)Av + (size_t)(brow + ar) * D_MODEL + ac;
    const unsigned short* Ap16base = (const unsigned short*)Av;

    float4 ra0, ra1, ra2, ra3;   // fp32 A in-flight regs

    auto stageB = [&](int k0, int buf) {
        #pragma unroll
        for (int r = 0; r < 2; ++r)
            gload_lds16(Wt + (size_t)(bcol + bsrow[r]) * D_MODEL + k0 + bsoff[r],
                        gsm + 16384 + buf * 8192 + bsdst[r]);
    };
    auto stageA16 = [&](int k0, int buf) {
        #pragma unroll
        for (int r = 0; r < 2; ++r)
            gload_lds16(Ap16base + (size_t)(brow + bsrow[r]) * D_MODEL + k0 + bsoff[r],
                        gsm + buf * 8192 + bsdst[r]);
    };
    auto loadA32 = [&](int k0) {
        ra0 = *(const float4*)(Ap32 + k0);
        ra1 = *(const float4*)(Ap32 + k0 + 4);
        ra2 = *(const float4*)(Ap32 + k0 + 8);
        ra3 = *(const float4*)(Ap32 + k0 + 12);
    };
    auto writeA32 = [&](int buf) {   // reg-dep wait retires B gloads issued earlier
        *(short8*)(gsm + buf * 8192 + awa[0]) = cvt8(ra0, ra1);
        *(short8*)(gsm + buf * 8192 + awa[1]) = cvt8(ra2, ra3);
    };

    // prologue: fill buf0
    if (A_FP32) {
        stageB(0, 0);
        loadA32(0);
        writeA32(0);
        barrier_lgkm();
    } else {
        stageA16(0, 0);
        stageB(0, 0);
        barrier_vm0();
    }

    for (int k0 = 0; k0 < D_MODEL; k0 += 128) {
        #pragma unroll
        for (int u = 0; u < 2; ++u) {
            const int kc = k0 + u * 64;
            const int kn = min(kc + 64, D_MODEL - 64);   // tail dup: harmless
            if (A_FP32) {
                stageB(kn, u ^ 1);
                loadA32(kn);
            } else {
                stageA16(kn, u ^ 1);
                stageB(kn, u ^ 1);
            }
            __builtin_amdgcn_sched_barrier(0);

            #pragma unroll
            for (int kstep = 0; kstep < 2; ++kstep) {
                short8 af[2], bf[2];
                #pragma unroll
                for (int m = 0; m < 2; ++m)
                    af[m] = *(const short8*)(gsm + u * 8192 + m * 2048 +
                                             (kstep ? a1 : a0));
                #pragma unroll
                for (int n = 0; n < 2; ++n)
                    bf[n] = *(const short8*)(gsm + u * 8192 + n * 2048 +
                                             (kstep ? b1r : b0r));
                #pragma unroll
                for (int m = 0; m < 2; ++m)
                    #pragma unroll
                    for (int n = 0; n < 2; ++n)
                        acc[m][n] = __builtin_amdgcn_mfma_f32_16x16x32_bf16(
                                        af[m], bf[n], acc[m][n], 0, 0, 0);
            }
            if (A_FP32) {
                writeA32(u ^ 1);
                barrier_lgkm();
            } else {
                barrier_vm0();
            }
        }
    }

    #pragma unroll
    for (int m = 0; m < 2; ++m)
        #pragma unroll
        for (int n = 0; n < 2; ++n) {
            const int col = bcol + wc * 32 + n * 16 + c;
            const float bval = bias[col];
            #pragma unroll
            for (int j = 0; j < 4; ++j) {
                const int row = brow + wr * 32 + m * 16 + g * 4 + j;
                const float val = (acc[m][n][j] + bval) * scale;
                if (OUT_BF16)
                    ((unsigned short*)C)[(size_t)row * D_MODEL + col] = f2bf1(val);
                else
                    ((float*)C)[(size_t)row * D_MODEL + col] = val;
            }
        }
}

// QKV: flat grid 2304, XCD-chunked so the 12 bcol-blocks sharing one A-panel
// run consecutively on ONE XCD (A-panel: 1 HBM fetch + 11 L2 hits).
// bid&7 -> xcd; per xcd: idx = z*96 + brow_local*12 + bcol (z-major keeps the
// hot A footprint per XCD at 8*196KB = 1.57 MB < 4 MB L2).
__global__ __launch_bounds__(256) void gemm_qkv_k(
    const float* __restrict__ query, const float* __restrict__ key,
    const float* __restrict__ value,
    const unsigned short* __restrict__ Wqt, const unsigned short* __restrict__ Wkt,
    const unsigned short* __restrict__ Wvt,
    const float* __restrict__ bq, const float* __restrict__ bk,
    const float* __restrict__ bv,
    unsigned short* __restrict__ qb, unsigned short* __restrict__ kb,
    unsigned short* __restrict__ vb)
{
    const int bid = blockIdx.x;
    const int xcd = bid & 7;
    const int idx = bid >> 3;          // 0..287
    const int z   = idx / 96;
    const int r   = idx % 96;
    const int brow = (xcd * 8 + r / 12) * 64;
    const int bcol = (r % 12) * 64;

    const void* A            = z == 0 ? (const void*)query : z == 1 ? (const void*)key : (const void*)value;
    const unsigned short* Wt = z == 0 ? Wqt : z == 1 ? Wkt : Wvt;
    const float* bias        = z == 0 ? bq  : z == 1 ? bk  : bv;
    unsigned short* C        = z == 0 ? qb  : z == 1 ? kb  : vb;
    gemm_body<1, 1>(A, Wt, bias, C, z == 0 ? QSCALE : 1.0f, brow, bcol);
}

__global__ __launch_bounds__(256) void gemm_o_k(
    const unsigned short* __restrict__ A, const unsigned short* __restrict__ Wt,
    const float* __restrict__ bias, float* __restrict__ C)
{
    const int bid = blockIdx.x;
    const int xcd = bid & 7;
    const int idx = bid >> 3;          // 0..95
    const int brow = (xcd * 8 + idx / 12) * 64;
    const int bcol = (idx % 12) * 64;
    gemm_body<0, 0>(A, Wt, bias, C, 1.0f, brow, bcol);
}

// ---------------- Flash attention: 2 bufs, unroll-2, lane-local defer -------
// grid 768 (flat, XCD-chunk swizzled), 256 thr = 4 waves; wave w: q-rows [16w,16w+16)
// LDS map (40 KB): K: 0 + buf*8192 ; V^T: 16384 + buf*8192 ; P: 32768 + w*2048
__global__ __launch_bounds__(256) void attn_mfma_k(
    const unsigned short* __restrict__ q, const unsigned short* __restrict__ k,
    const unsigned short* __restrict__ v, unsigned short* __restrict__ ctx)
{
    __shared__ __align__(16) char sm[40960];

    const int tid  = threadIdx.x;
    const int w    = tid >> 6;
    const int lane = tid & 63;
    const int g    = lane >> 4;
    const int c    = lane & 15;

    const int bid = blockIdx.x;
    const int swz = (bid & 7) * 96 + (bid >> 3);
    const int qt  = swz & 31;
    const int hb  = swz >> 5;
    const int h   = hb % HEADS;
    const int b   = hb / HEADS;
    const int q0  = qt * 64;
    const int NT  = SEQ / 64;   // 32

    // Q strip A-frags (pre-scaled by QSCALE in the projection GEMM)
    short8 qf0, qf1;
    {
        const int qrow = q0 + (w << 4) + c;
        const unsigned short* qp = q + (size_t)(b * SEQ + qrow) * D_MODEL + h * DK;
        qf0 = *(const short8*)(qp + g * 8);
        qf1 = *(const short8*)(qp + 32 + g * 8);
    }

    float m_run[4] = {-INFINITY, -INFINITY, -INFINITY, -INFINITY};
    f32x4 lacc = f32x4{0, 0, 0, 0};
    f32x4 o[4] = {f32x4{0,0,0,0}, f32x4{0,0,0,0}, f32x4{0,0,0,0}, f32x4{0,0,0,0}};
    const short8 ONES = {0x3F80, 0x3F80, 0x3F80, 0x3F80,
                         0x3F80, 0x3F80, 0x3F80, 0x3F80};

    // hoisted LDS read bases (row&7 == c&7 for K/V/P fragment rows)
    const int xc = (c & 7) << 4;
    const int rb0 = c * 128 + ((g * 16) ^ xc);        // kstep 0
    const int rb1 = c * 128 + ((64 + g * 16) ^ xc);   // kstep 1
    const int bp0 = 32768 + w * 2048 + rb0;           // P read bases
    const int bp1 = 32768 + w * 2048 + rb1;

    // P write addresses (per reg)
    int pwa[4];
    #pragma unroll
    for (int r = 0; r < 4; ++r) {
        const int row = (g << 2) + r;
        pwa[r] = 32768 + w * 2048 + row * 128 + ((c << 3) ^ ((row & 7) << 4));
    }
    // V write addresses (per j)
    const int cv = tid & 15, vd0 = (tid >> 4) << 2;
    int vwa[4];
    #pragma unroll
    for (int j = 0; j < 4; ++j) {
        const int row = vd0 + j;
        vwa[j] = 16384 + row * 128 + ((cv << 3) ^ ((row & 7) << 4));
    }
    // K staging geometry (linear dest + pre-swizzled source)
    int kdst[2];
    const unsigned short* kg[2];
    {
        const unsigned short* kbase = k + (size_t)(b * SEQ) * D_MODEL + h * DK;
        #pragma unroll
        for (int r = 0; r < 2; ++r) {
            int phys = (w + 4 * r) * 1024 + lane * 16;
            int row  = phys >> 7;
            int slot = (phys >> 4) & 7;
            kdst[r]  = (w + 4 * r) * 1024;
            kg[r]    = kbase + (size_t)row * D_MODEL + (slot ^ (row & 7)) * 8;
        }
    }
    const unsigned short* vg = v + (size_t)(b * SEQ + cv) * D_MODEL + h * DK + vd0;
    const int TS = 64 * D_MODEL;   // tile stride (elements)

    us4 va, vb_, vc, vd;   // V in-flight regs (single set, write-late)

    // ---- prologue: tile 0 ----
    gload_lds16(kg[0], sm + kdst[0]);
    gload_lds16(kg[1], sm + kdst[1]);
    va  = *(const us4*)(vg);
    vb_ = *(const us4*)(vg + 16 * D_MODEL);
    vc  = *(const us4*)(vg + 32 * D_MODEL);
    vd  = *(const us4*)(vg + 48 * D_MODEL);
    kg[0] += TS; kg[1] += TS; vg += TS;
    #pragma unroll
    for (int j = 0; j < 4; ++j) {
        uint2 pk;
        pk.x = (unsigned)va[j] | ((unsigned)vb_[j] << 16);
        pk.y = (unsigned)vc[j] | ((unsigned)vd[j] << 16);
        *(uint2*)(sm + vwa[j]) = pk;
    }
    barrier_lgkm();

    for (int kt = 0; kt < NT; kt += 2) {
        #pragma unroll
        for (int u = 0; u < 2; ++u) {
            // ---- prefetch tile kt+u+1 (tail overruns stay inside d_ws, unused) ----
            gload_lds16(kg[0], sm + (u ^ 1) * 8192 + kdst[0]);
            gload_lds16(kg[1], sm + (u ^ 1) * 8192 + kdst[1]);
            va  = *(const us4*)(vg);
            vb_ = *(const us4*)(vg + 16 * D_MODEL);
            vc  = *(const us4*)(vg + 32 * D_MODEL);
            vd  = *(const us4*)(vg + 48 * D_MODEL);
            kg[0] += TS; kg[1] += TS; vg += TS;
            __builtin_amdgcn_sched_barrier(0);

            // ---- S = Q @ K^T ----
            f32x4 sacc[4] = {f32x4{0,0,0,0}, f32x4{0,0,0,0},
                             f32x4{0,0,0,0}, f32x4{0,0,0,0}};
            #pragma unroll
            for (int kstep = 0; kstep < 2; ++kstep) {
                short8 af = kstep ? qf1 : qf0;
                #pragma unroll
                for (int ks = 0; ks < 4; ++ks) {
                    short8 bf = *(const short8*)(sm + u * 8192 + ks * 2048 +
                                                 (kstep ? rb1 : rb0));
                    sacc[ks] = __builtin_amdgcn_mfma_f32_16x16x32_bf16(
                                   af, bf, sacc[ks], 0, 0, 0);
                }
            }

            // ---- defer-max check: lane-local, ZERO cross-lane ops ----
            float rm[4], dm;
            #pragma unroll
            for (int reg = 0; reg < 4; ++reg)
                rm[reg] = fmaxf(fmaxf(sacc[0][reg], sacc[1][reg]),
                                fmaxf(sacc[2][reg], sacc[3][reg]));
            dm = fmaxf(fmaxf(rm[0] - m_run[0], rm[1] - m_run[1]),
                       fmaxf(rm[2] - m_run[2], rm[3] - m_run[3]));
            if (__any(dm > 11.0f)) {   // rare slow path: full row-max + rescale
                #pragma unroll
                for (int reg = 0; reg < 4; ++reg) {
                    float mx = rm[reg];
                    mx = fmaxf(mx, __shfl_xor(mx, 1));
                    mx = fmaxf(mx, __shfl_xor(mx, 2));
                    mx = fmaxf(mx, __shfl_xor(mx, 4));
                    mx = fmaxf(mx, __shfl_xor(mx, 8));
                    const float mnew = fmaxf(m_run[reg], mx);
                    const float sc = fast_exp2(m_run[reg] - mnew);
                    m_run[reg] = mnew;
                    lacc[reg] *= sc;
                    o[0][reg] *= sc;
                    o[1][reg] *= sc;
                    o[2][reg] *= sc;
                    o[3][reg] *= sc;
                }
            }
            #pragma unroll
            for (int reg = 0; reg < 4; ++reg) {
                const float m = m_run[reg];
                float p0 = fast_exp2(sacc[0][reg] - m);
                float p1 = fast_exp2(sacc[1][reg] - m);
                float p2 = fast_exp2(sacc[2][reg] - m);
                float p3 = fast_exp2(sacc[3][reg] - m);
                uint2 pw;
                pw.x = f2bf2(p0, p1);
                pw.y = f2bf2(p2, p3);
                *(uint2*)(sm + pwa[reg]) = pw;
            }

            // ---- O += P @ V ; l += P @ ones ----
            #pragma unroll
            for (int kstep = 0; kstep < 2; ++kstep) {
                short8 paf = *(const short8*)(sm + (kstep ? bp1 : bp0));
                lacc = __builtin_amdgcn_mfma_f32_16x16x32_bf16(paf, ONES, lacc, 0, 0, 0);
                #pragma unroll
                for (int dsub = 0; dsub < 4; ++dsub) {
                    short8 vbf = *(const short8*)(sm + 16384 + u * 8192 +
                                                  dsub * 2048 + (kstep ? rb1 : rb0));
                    o[dsub] = __builtin_amdgcn_mfma_f32_16x16x32_bf16(
                                  paf, vbf, o[dsub], 0, 0, 0);
                }
            }

            // ---- V(kt+u+1) regs -> LDS (reg-dep retires this tile's prefetch) ----
            #pragma unroll
            for (int j = 0; j < 4; ++j) {
                uint2 pk;
                pk.x = (unsigned)va[j] | ((unsigned)vb_[j] << 16);
                pk.y = (unsigned)vc[j] | ((unsigned)vd[j] << 16);
                *(uint2*)(sm + (u ^ 1) * 8192 + vwa[j]) = pk;
            }
            barrier_lgkm();
        }
    }

    // ---- normalize, store ctx as bf16 ----
    #pragma unroll
    for (int reg = 0; reg < 4; ++reg) {
        const int qrow = q0 + (w << 4) + (g << 2) + reg;
        unsigned short* cb = ctx + (size_t)(b * SEQ + qrow) * D_MODEL + h * DK;
        const float invl = 1.f / lacc[reg];
        #pragma unroll
        for (int dsub = 0; dsub < 4; ++dsub)
            cb[dsub * 16 + c] = f2bf1(o[dsub][reg] * invl);
    }
}

// ---------------------------------------------------------------------------
extern "C" void kernel_launch(void* const* d_in, const int* in_sizes, int n_in,
                              void* d_out, int out_size, void* d_ws, size_t ws_size,
                              hipStream_t stream) {
    const float* query = (const float*)d_in[0];
    const float* key   = (const float*)d_in[1];
    const float* value = (const float*)d_in[2];
    const float* Wq = (const float*)d_in[3];
    const float* bq = (const float*)d_in[4];
    const float* Wk = (const float*)d_in[5];
    const float* bk = (const float*)d_in[6];
    const float* Wv = (const float*)d_in[7];
    const float* bv = (const float*)d_in[8];
    const float* Wo = (const float*)d_in[9];
    const float* bo = (const float*)d_in[10];
    float* out = (float*)d_out;

    const size_t mat = (size_t)MTOT * D_MODEL;      // 3.145M elems
    unsigned short* qb  = (unsigned short*)d_ws;    // projected Q/K/V (bf16)
    unsigned short* kb  = qb + mat;
    unsigned short* vb  = kb + mat;
    unsigned short* cb  = vb + mat;                 // context (bf16)
    unsigned short* Wqt = cb + mat;                 // transposed bf16 weights
    unsigned short* Wkt = Wqt + D_MODEL * D_MODEL;
    unsigned short* Wvt = Wkt + D_MODEL * D_MODEL;
    unsigned short* Wot = Wvt + D_MODEL * D_MODEL;

    cvt_wt_k<<<dim3(D_MODEL / 32, D_MODEL / 32, 4), 256, 0, stream>>>(
        Wq, Wk, Wv, Wo, Wqt, Wkt, Wvt, Wot);

    gemm_qkv_k<<<dim3(3 * 64 * 12), 256, 0, stream>>>(
        query, key, value, Wqt, Wkt, Wvt, bq, bk, bv, qb, kb, vb);

    attn_mfma_k<<<dim3(SEQ / 64 * HEADS * BATCH), 256, 0, stream>>>(qb, kb, vb, cb);

    gemm_o_k<<<dim3(64 * 12), 256, 0, stream>>>(cb, Wot, bo, out);
}